// Round 5
// baseline (296.074 us; speedup 1.0000x reference)
//
#include <hip/hip_runtime.h>
#include <hip/hip_bf16.h>

#define G_   16
#define DG_  128
#define F_   2048
#define N_   2048
#define M_   2048

typedef __attribute__((ext_vector_type(8))) short s16x8;   // 8 bf16 (4 VGPRs)
typedef __attribute__((ext_vector_type(4))) float f32x4;
typedef __attribute__((ext_vector_type(2))) unsigned int u32x2;

typedef const __attribute__((address_space(1))) void GV;
typedef __attribute__((address_space(3))) void LV;

__device__ inline unsigned short f2bf(float f) {           // RN-even fp32->bf16
  unsigned u = __float_as_uint(f);
  u += 0x7fffu + ((u >> 16) & 1u);
  return (unsigned short)(u >> 16);
}

// ---------------- fp32 -> bf16 convert: 5 arrays in one launch -----------
struct Cvt5Args { const float* s[5]; unsigned short* d[5]; };

__global__ __launch_bounds__(256)
void cvt5(Cvt5Args a) {
  unsigned u = blockIdx.x * 256 + threadIdx.x;
  if (u >= 5u * 524288u) return;
  int seg = u >> 19;                 // 524288 = 2^19 eights per 4M array
  unsigned off = u & 524287u;
  const float4* sp = (const float4*)(a.s[seg] + (size_t)off * 8);
  float4 x = sp[0], y = sp[1];
  uint4 o;
  o.x = (unsigned)f2bf(x.x) | ((unsigned)f2bf(x.y) << 16);
  o.y = (unsigned)f2bf(x.z) | ((unsigned)f2bf(x.w) << 16);
  o.z = (unsigned)f2bf(y.x) | ((unsigned)f2bf(y.y) << 16);
  o.w = (unsigned)f2bf(y.z) | ((unsigned)f2bf(y.w) << 16);
  *(uint4*)(a.d[seg] + (size_t)off * 8) = o;
}

__global__ __launch_bounds__(256)
void cvt_bf16(const float* __restrict__ s, unsigned short* __restrict__ d, int n8) {
  int i = blockIdx.x * 256 + threadIdx.x;
  if (i >= n8) return;
  const float4* sp = (const float4*)(s + (size_t)i * 8);
  float4 a = sp[0], b = sp[1];
  uint4 o;
  o.x = (unsigned)f2bf(a.x) | ((unsigned)f2bf(a.y) << 16);
  o.y = (unsigned)f2bf(a.z) | ((unsigned)f2bf(a.w) << 16);
  o.z = (unsigned)f2bf(b.x) | ((unsigned)f2bf(b.y) << 16);
  o.w = (unsigned)f2bf(b.z) | ((unsigned)f2bf(b.w) << 16);
  *(uint4*)(d + (size_t)i * 8) = o;
}

// ---------------- bf16 NT GEMM, 3 jobs fused: C = A @ B^T + bias ---------
// All jobs 2048^3. 128x128 tile, BK=64, 2-phase, XOR-swizzled LDS.
struct GemmJobs {
  const unsigned short* A[3];
  const unsigned short* B[3];
  const float* bias[3];
  unsigned short* C[3];
};

__global__ __launch_bounds__(256, 2)
void gemm3(GemmJobs jb, int jbase) {
  __shared__ unsigned short As[2][128 * 64];
  __shared__ unsigned short Bs[2][128 * 64];
  const int j = jbase + (blockIdx.x >> 8);
  const int bs = blockIdx.x & 255;
  const unsigned short* A = jb.A[j];
  const unsigned short* B = jb.B[j];
  const float* bias = jb.bias[j];
  unsigned short* C = jb.C[j];

  const int tid = threadIdx.x, lane = tid & 63, wv = tid >> 6;
  const int wm = wv >> 1, wn = wv & 1;
  const int l15 = lane & 15, l4 = lane >> 4;
  const int m0 = (bs >> 4) * 128, n0 = (bs & 15) * 128;

  f32x4 acc[4][4];
#pragma unroll
  for (int i = 0; i < 4; ++i)
#pragma unroll
    for (int jj = 0; jj < 4; ++jj) acc[i][jj] = (f32x4){0.f, 0.f, 0.f, 0.f};

  const int ksw = (((lane & 7) ^ (lane >> 3)) * 8);
  const size_t baseA = (size_t)(m0 + wv * 32 + (lane >> 3)) * F_ + ksw;
  const size_t baseB = (size_t)(n0 + wv * 32 + (lane >> 3)) * F_ + ksw;

  auto stage = [&](int buf, int k0) {
#pragma unroll
    for (int i = 0; i < 4; ++i) {
      __builtin_amdgcn_global_load_lds((GV*)(A + baseA + (size_t)i * 8 * F_ + k0),
                                       (LV*)(&As[buf][(wv * 32 + i * 8) * 64]), 16, 0, 0);
      __builtin_amdgcn_global_load_lds((GV*)(B + baseB + (size_t)i * 8 * F_ + k0),
                                       (LV*)(&Bs[buf][(wv * 32 + i * 8) * 64]), 16, 0, 0);
    }
  };

  stage(0, 0);
  __syncthreads();
  int cur = 0;
  const int xorb = (l15 & 7) << 4;
  const int csw0 = (l4 * 16) ^ xorb;
  const int csw1 = (64 + l4 * 16) ^ xorb;

  const int NT = F_ / 64;
  for (int t = 0; t < NT; ++t) {
    if (t + 1 < NT) stage(cur ^ 1, (t + 1) * 64);
    const unsigned short* Ab = &As[cur][0];
    const unsigned short* Bb = &Bs[cur][0];
#pragma unroll
    for (int kc = 0; kc < 2; ++kc) {
      const int cs = kc ? csw1 : csw0;
      s16x8 af[4], bf[4];
#pragma unroll
      for (int i = 0; i < 4; ++i)
        af[i] = *(const s16x8*)((const char*)Ab + (wm * 64 + i * 16 + l15) * 128 + cs);
#pragma unroll
      for (int i = 0; i < 4; ++i)
        bf[i] = *(const s16x8*)((const char*)Bb + (wn * 64 + i * 16 + l15) * 128 + cs);
      __builtin_amdgcn_s_setprio(1);
#pragma unroll
      for (int am = 0; am < 4; ++am)
#pragma unroll
        for (int bn = 0; bn < 4; ++bn)
          acc[am][bn] = __builtin_amdgcn_mfma_f32_16x16x32_bf16(af[am], bf[bn], acc[am][bn], 0, 0, 0);
      __builtin_amdgcn_s_setprio(0);
    }
    __syncthreads();
    cur ^= 1;
  }

#pragma unroll
  for (int bn = 0; bn < 4; ++bn) {
    int c = n0 + wn * 64 + bn * 16 + l15;
    float bv = bias ? bias[c] : 0.f;
#pragma unroll
    for (int am = 0; am < 4; ++am) {
#pragma unroll
      for (int jj = 0; jj < 4; ++jj) {
        int r = m0 + wm * 64 + am * 16 + l4 * 4 + jj;
        C[(size_t)r * F_ + c] = f2bf(acc[am][bn][jj] + bv);
      }
    }
  }
}

// ---------------- flash attention: KVBLK=128, single-buffer + reg-stage --
// Block: (64 q, 1 group) = 4 waves x 16 q. LDS 80KB: Kt[128][128],
// Vts[128][128] (V^T), Pt[4][16][128]. All rows 256B, XOR-swizzled
// (byte ^= (row&7)<<4). T14: loads for t+1 issue at iter top into regs,
// ds_write after the compute barrier. T13 defer-max. T5 setprio.
__global__ __launch_bounds__(256, 2)
void attn_mfma(const unsigned short* __restrict__ Q,
               const unsigned short* __restrict__ K,
               const unsigned short* __restrict__ Vt,
               const float* __restrict__ vb,
               float* __restrict__ out) {
  __shared__ unsigned short Kt[128 * 128];
  __shared__ unsigned short Vts[128 * 128];
  __shared__ unsigned short Pt[4][16 * 128];
  const int tid = threadIdx.x, lane = tid & 63, wv = tid >> 6;
  const int l15 = lane & 15, l4 = lane >> 4;
  const int g = blockIdx.y;
  const int q0 = blockIdx.x * 64 + wv * 16;

  s16x8 qa[4];
#pragma unroll
  for (int kc = 0; kc < 4; ++kc)
    qa[kc] = *(const s16x8*)(Q + (size_t)(q0 + l15) * F_ + g * DG_ + kc * 32 + l4 * 8);

  f32x4 oa[8];
#pragma unroll
  for (int df = 0; df < 8; ++df) oa[df] = (f32x4){0.f, 0.f, 0.f, 0.f};
  float m_r = -1e30f, l_r = 0.f;
  const float cscale = 0.12751664508246770f;  // (1/sqrt(128)) * log2(e)

  // staging: thread -> (row sr, 128B-half sh); 8 x uint4 each for K and V
  const int sr = tid >> 1;
  const int sh = (tid & 1) * 128;                       // byte offset in row
  const unsigned short* gK = K + (size_t)sr * F_ + g * DG_ + (tid & 1) * 64;
  const unsigned short* gV = Vt + (size_t)(g * DG_ + sr) * M_ + (tid & 1) * 64;
  const int swr = (sr & 7) << 4;

  uint4 kst[8], vst[8];
#pragma unroll
  for (int i = 0; i < 8; ++i) kst[i] = *(const uint4*)(gK + i * 8);
#pragma unroll
  for (int i = 0; i < 8; ++i) vst[i] = *(const uint4*)(gV + i * 8);
#pragma unroll
  for (int i = 0; i < 8; ++i)
    *(uint4*)((char*)Kt + sr * 256 + ((sh + i * 16) ^ swr)) = kst[i];
#pragma unroll
  for (int i = 0; i < 8; ++i)
    *(uint4*)((char*)Vts + sr * 256 + ((sh + i * 16) ^ swr)) = vst[i];
  __syncthreads();

  unsigned short* Pw = &Pt[wv][0];
  const int xorb = (l15 & 7) << 4;
  int csw[4];
#pragma unroll
  for (int kc = 0; kc < 4; ++kc) csw[kc] = (kc * 64 + l4 * 16) ^ xorb;

  for (int t = 0; t < M_ / 128; ++t) {
    // ---- issue prefetch for t+1 into regs (hidden under compute) ----
    if (t + 1 < M_ / 128) {
#pragma unroll
      for (int i = 0; i < 8; ++i)
        kst[i] = *(const uint4*)(gK + (size_t)(t + 1) * 128 * F_ + i * 8);
#pragma unroll
      for (int i = 0; i < 8; ++i)
        vst[i] = *(const uint4*)(gV + (size_t)(t + 1) * 128 + i * 8);
    }

    // ---- S^T = K Q^T : lane q=l15, kv = kvf*16 + l4*4 + j ----
    f32x4 sf[8];
    __builtin_amdgcn_s_setprio(1);
#pragma unroll
    for (int kvf = 0; kvf < 8; ++kvf) {
      const char* kr = (const char*)Kt + (kvf * 16 + l15) * 256;
      f32x4 s = (f32x4){0.f, 0.f, 0.f, 0.f};
#pragma unroll
      for (int kc = 0; kc < 4; ++kc)
        s = __builtin_amdgcn_mfma_f32_16x16x32_bf16(*(const s16x8*)(kr + csw[kc]), qa[kc], s, 0, 0, 0);
      sf[kvf] = s;
    }
    __builtin_amdgcn_s_setprio(0);

    // ---- online softmax with defer-max (THR=8 in log2 domain) ----
    float tmax = sf[0][0];
#pragma unroll
    for (int kvf = 0; kvf < 8; ++kvf)
#pragma unroll
      for (int j = 0; j < 4; ++j) tmax = fmaxf(tmax, sf[kvf][j]);
    tmax = fmaxf(tmax, __shfl_xor(tmax, 16));
    tmax = fmaxf(tmax, __shfl_xor(tmax, 32));
    tmax *= cscale;
    if (!__all(tmax <= m_r + 8.0f)) {
      float mnew = fmaxf(m_r, tmax);
      float corr = __builtin_amdgcn_exp2f(m_r - mnew);
      m_r = mnew;
      l_r *= corr;
      float c0 = __shfl(corr, l4 * 4 + 0);
      float c1 = __shfl(corr, l4 * 4 + 1);
      float c2 = __shfl(corr, l4 * 4 + 2);
      float c3 = __shfl(corr, l4 * 4 + 3);
#pragma unroll
      for (int df = 0; df < 8; ++df) {
        oa[df][0] *= c0; oa[df][1] *= c1; oa[df][2] *= c2; oa[df][3] *= c3;
      }
    }

    float psum = 0.f;
#pragma unroll
    for (int kvf = 0; kvf < 8; ++kvf) {
      float p0 = __builtin_amdgcn_exp2f(sf[kvf][0] * cscale - m_r);
      float p1 = __builtin_amdgcn_exp2f(sf[kvf][1] * cscale - m_r);
      float p2 = __builtin_amdgcn_exp2f(sf[kvf][2] * cscale - m_r);
      float p3 = __builtin_amdgcn_exp2f(sf[kvf][3] * cscale - m_r);
      psum += (p0 + p1) + (p2 + p3);
      u32x2 w;
      w.x = (unsigned)f2bf(p0) | ((unsigned)f2bf(p1) << 16);
      w.y = (unsigned)f2bf(p2) | ((unsigned)f2bf(p3) << 16);
      *(u32x2*)((char*)Pw + l15 * 256 + ((kvf * 32 + l4 * 8) ^ xorb)) = w;
    }
    psum += __shfl_xor(psum, 16);
    psum += __shfl_xor(psum, 32);
    l_r += psum;

    // ---- O += P V ----
    s16x8 pa[4];
#pragma unroll
    for (int kc2 = 0; kc2 < 4; ++kc2)
      pa[kc2] = *(const s16x8*)((const char*)Pw + l15 * 256 + csw[kc2]);
    __builtin_amdgcn_s_setprio(1);
#pragma unroll
    for (int df = 0; df < 8; ++df) {
      const char* vr = (const char*)Vts + (df * 16 + l15) * 256;
#pragma unroll
      for (int kc2 = 0; kc2 < 4; ++kc2)
        oa[df] = __builtin_amdgcn_mfma_f32_16x16x32_bf16(pa[kc2], *(const s16x8*)(vr + csw[kc2]), oa[df], 0, 0, 0);
    }
    __builtin_amdgcn_s_setprio(0);
    __syncthreads();               // all waves done reading Kt/Vts

    if (t + 1 < M_ / 128) {
#pragma unroll
      for (int i = 0; i < 8; ++i)
        *(uint4*)((char*)Kt + sr * 256 + ((sh + i * 16) ^ swr)) = kst[i];
#pragma unroll
      for (int i = 0; i < 8; ++i)
        *(uint4*)((char*)Vts + sr * 256 + ((sh + i * 16) ^ swr)) = vst[i];
      __syncthreads();             // tile t+1 ready
    }
  }

  // ---- epilogue ----
  float linv = 1.0f / l_r;
  float i0 = __shfl(linv, l4 * 4 + 0);
  float i1 = __shfl(linv, l4 * 4 + 1);
  float i2 = __shfl(linv, l4 * 4 + 2);
  float i3 = __shfl(linv, l4 * 4 + 3);
#pragma unroll
  for (int df = 0; df < 8; ++df) {
    int c = g * DG_ + df * 16 + l15;
    float bv = vb[c];
    out[(size_t)(q0 + l4 * 4 + 0) * F_ + c] = oa[df][0] * i0 + bv;
    out[(size_t)(q0 + l4 * 4 + 1) * F_ + c] = oa[df][1] * i1 + bv;
    out[(size_t)(q0 + l4 * 4 + 2) * F_ + c] = oa[df][2] * i2 + bv;
    out[(size_t)(q0 + l4 * 4 + 3) * F_ + c] = oa[df][3] * i3 + bv;
  }
}

extern "C" void kernel_launch(void* const* d_in, const int* in_sizes, int n_in,
                              void* d_out, int out_size, void* d_ws, size_t ws_size,
                              hipStream_t stream) {
  const float* roi  = (const float*)d_in[0];
  const float* ref  = (const float*)d_in[1];
  const float* Wq_w = (const float*)d_in[2];
  const float* Wq_b = (const float*)d_in[3];
  const float* Wk_w = (const float*)d_in[4];
  const float* Wk_b = (const float*)d_in[5];
  const float* Wv_w = (const float*)d_in[6];
  const float* Wv_b = (const float*)d_in[7];
  float* out = (float*)d_out;
  const size_t SEG = 4194304;  // 8 MB / 2B

  if (ws_size >= 64ull * 1024 * 1024) {
    unsigned short* roi_bf = (unsigned short*)d_ws;
    unsigned short* ref_bf = roi_bf + SEG;
    unsigned short* Wq_bf  = ref_bf + SEG;
    unsigned short* Wk_bf  = Wq_bf + SEG;
    unsigned short* Wv_bf  = Wk_bf + SEG;
    unsigned short* Qb     = Wv_bf + SEG;
    unsigned short* Kb     = Qb + SEG;
    unsigned short* Vtb    = Kb + SEG;

    Cvt5Args ca;
    ca.s[0] = roi;  ca.d[0] = roi_bf;
    ca.s[1] = ref;  ca.d[1] = ref_bf;
    ca.s[2] = Wq_w; ca.d[2] = Wq_bf;
    ca.s[3] = Wk_w; ca.d[3] = Wk_bf;
    ca.s[4] = Wv_w; ca.d[4] = Wv_bf;
    cvt5<<<10240, 256, 0, stream>>>(ca);

    GemmJobs jb;
    jb.A[0] = roi_bf; jb.B[0] = Wq_bf;  jb.bias[0] = Wq_b;    jb.C[0] = Qb;
    jb.A[1] = ref_bf; jb.B[1] = Wk_bf;  jb.bias[1] = Wk_b;    jb.C[1] = Kb;
    jb.A[2] = Wv_bf;  jb.B[2] = ref_bf; jb.bias[2] = nullptr; jb.C[2] = Vtb;
    gemm3<<<768, 256, 0, stream>>>(jb, 0);

    attn_mfma<<<dim3(N_ / 64, G_), 256, 0, stream>>>(Qb, Kb, Vtb, Wv_b, out);
  } else {
    if (ws_size < 48ull * 1024 * 1024) return;
    unsigned short* roi_bf = (unsigned short*)d_ws;
    unsigned short* ref_bf = roi_bf + SEG;
    unsigned short* W_bf   = ref_bf + SEG;
    unsigned short* Qb     = W_bf + SEG;
    unsigned short* Kb     = Qb + SEG;
    unsigned short* Vtb    = Kb + SEG;
    const int n8 = (N_ * F_) / 8;

    cvt_bf16<<<2048, 256, 0, stream>>>(roi, roi_bf, n8);
    cvt_bf16<<<2048, 256, 0, stream>>>(ref, ref_bf, n8);

    GemmJobs jb;
    jb.A[0] = roi_bf; jb.B[0] = W_bf;   jb.bias[0] = Wq_b;    jb.C[0] = Qb;
    jb.A[1] = ref_bf; jb.B[1] = W_bf;   jb.bias[1] = Wk_b;    jb.C[1] = Kb;
    jb.A[2] = W_bf;   jb.B[2] = ref_bf; jb.bias[2] = nullptr; jb.C[2] = Vtb;

    cvt_bf16<<<2048, 256, 0, stream>>>(Wq_w, W_bf, n8);
    gemm3<<<256, 256, 0, stream>>>(jb, 0);
    cvt_bf16<<<2048, 256, 0, stream>>>(Wk_w, W_bf, n8);
    gemm3<<<256, 256, 0, stream>>>(jb, 1);
    cvt_bf16<<<2048, 256, 0, stream>>>(Wv_w, W_bf, n8);
    gemm3<<<256, 256, 0, stream>>>(jb, 2);

    attn_mfma<<<dim3(N_ / 64, G_), 256, 0, stream>>>(Qb, Kb, Vtb, Wv_b, out);
  }
}

// Round 6
// 150.278 us; speedup vs baseline: 1.9702x; 1.9702x over previous
//
#include <hip/hip_runtime.h>
#include <hip/hip_bf16.h>

#define G_   16
#define DG_  128
#define F_   2048
#define N_   2048
#define M_   2048

typedef __attribute__((ext_vector_type(8))) short s16x8;   // 8 bf16 (4 VGPRs)
typedef __attribute__((ext_vector_type(4))) float f32x4;
typedef __attribute__((ext_vector_type(2))) unsigned int u32x2;

typedef const __attribute__((address_space(1))) void GV;
typedef __attribute__((address_space(3))) void LV;

__device__ inline unsigned short f2bf(float f) {           // RN-even fp32->bf16
  unsigned u = __float_as_uint(f);
  u += 0x7fffu + ((u >> 16) & 1u);
  return (unsigned short)(u >> 16);
}

// ---------------- fp32 -> bf16 convert: 5 arrays in one launch -----------
struct Cvt5Args { const float* s[5]; unsigned short* d[5]; };

__global__ __launch_bounds__(256)
void cvt5(Cvt5Args a) {
  unsigned u = blockIdx.x * 256 + threadIdx.x;
  if (u >= 5u * 524288u) return;
  int seg = u >> 19;                 // 524288 = 2^19 eights per 4M array
  unsigned off = u & 524287u;
  const float4* sp = (const float4*)(a.s[seg] + (size_t)off * 8);
  float4 x = sp[0], y = sp[1];
  uint4 o;
  o.x = (unsigned)f2bf(x.x) | ((unsigned)f2bf(x.y) << 16);
  o.y = (unsigned)f2bf(x.z) | ((unsigned)f2bf(x.w) << 16);
  o.z = (unsigned)f2bf(y.x) | ((unsigned)f2bf(y.y) << 16);
  o.w = (unsigned)f2bf(y.z) | ((unsigned)f2bf(y.w) << 16);
  *(uint4*)(a.d[seg] + (size_t)off * 8) = o;
}

__global__ __launch_bounds__(256)
void cvt_bf16(const float* __restrict__ s, unsigned short* __restrict__ d, int n8) {
  int i = blockIdx.x * 256 + threadIdx.x;
  if (i >= n8) return;
  const float4* sp = (const float4*)(s + (size_t)i * 8);
  float4 a = sp[0], b = sp[1];
  uint4 o;
  o.x = (unsigned)f2bf(a.x) | ((unsigned)f2bf(a.y) << 16);
  o.y = (unsigned)f2bf(a.z) | ((unsigned)f2bf(a.w) << 16);
  o.z = (unsigned)f2bf(b.x) | ((unsigned)f2bf(b.y) << 16);
  o.w = (unsigned)f2bf(b.z) | ((unsigned)f2bf(b.w) << 16);
  *(uint4*)(d + (size_t)i * 8) = o;
}

// ---------------- bf16 NT GEMM, 3 jobs fused: C = (A @ B^T + bias)*osc ---
// All jobs 2048^3. 128x128 tile, BK=64, 2-phase, XOR-swizzled LDS.
struct GemmJobs {
  const unsigned short* A[3];
  const unsigned short* B[3];
  const float* bias[3];
  unsigned short* C[3];
  float osc[3];
};

__global__ __launch_bounds__(256, 2)
void gemm3(GemmJobs jb, int jbase) {
  __shared__ unsigned short As[2][128 * 64];
  __shared__ unsigned short Bs[2][128 * 64];
  const int j = jbase + (blockIdx.x >> 8);
  const int bs = blockIdx.x & 255;
  const unsigned short* A = jb.A[j];
  const unsigned short* B = jb.B[j];
  const float* bias = jb.bias[j];
  unsigned short* C = jb.C[j];
  const float osc = jb.osc[j];

  const int tid = threadIdx.x, lane = tid & 63, wv = tid >> 6;
  const int wm = wv >> 1, wn = wv & 1;
  const int l15 = lane & 15, l4 = lane >> 4;
  const int m0 = (bs >> 4) * 128, n0 = (bs & 15) * 128;

  f32x4 acc[4][4];
#pragma unroll
  for (int i = 0; i < 4; ++i)
#pragma unroll
    for (int jj = 0; jj < 4; ++jj) acc[i][jj] = (f32x4){0.f, 0.f, 0.f, 0.f};

  const int ksw = (((lane & 7) ^ (lane >> 3)) * 8);
  const size_t baseA = (size_t)(m0 + wv * 32 + (lane >> 3)) * F_ + ksw;
  const size_t baseB = (size_t)(n0 + wv * 32 + (lane >> 3)) * F_ + ksw;

  auto stage = [&](int buf, int k0) {
#pragma unroll
    for (int i = 0; i < 4; ++i) {
      __builtin_amdgcn_global_load_lds((GV*)(A + baseA + (size_t)i * 8 * F_ + k0),
                                       (LV*)(&As[buf][(wv * 32 + i * 8) * 64]), 16, 0, 0);
      __builtin_amdgcn_global_load_lds((GV*)(B + baseB + (size_t)i * 8 * F_ + k0),
                                       (LV*)(&Bs[buf][(wv * 32 + i * 8) * 64]), 16, 0, 0);
    }
  };

  stage(0, 0);
  __syncthreads();
  int cur = 0;
  const int xorb = (l15 & 7) << 4;
  const int csw0 = (l4 * 16) ^ xorb;
  const int csw1 = (64 + l4 * 16) ^ xorb;

  const int NT = F_ / 64;
  for (int t = 0; t < NT; ++t) {
    if (t + 1 < NT) stage(cur ^ 1, (t + 1) * 64);
    const unsigned short* Ab = &As[cur][0];
    const unsigned short* Bb = &Bs[cur][0];
#pragma unroll
    for (int kc = 0; kc < 2; ++kc) {
      const int cs = kc ? csw1 : csw0;
      s16x8 af[4], bf[4];
#pragma unroll
      for (int i = 0; i < 4; ++i)
        af[i] = *(const s16x8*)((const char*)Ab + (wm * 64 + i * 16 + l15) * 128 + cs);
#pragma unroll
      for (int i = 0; i < 4; ++i)
        bf[i] = *(const s16x8*)((const char*)Bb + (wn * 64 + i * 16 + l15) * 128 + cs);
      __builtin_amdgcn_s_setprio(1);
#pragma unroll
      for (int am = 0; am < 4; ++am)
#pragma unroll
        for (int bn = 0; bn < 4; ++bn)
          acc[am][bn] = __builtin_amdgcn_mfma_f32_16x16x32_bf16(af[am], bf[bn], acc[am][bn], 0, 0, 0);
      __builtin_amdgcn_s_setprio(0);
    }
    __syncthreads();
    cur ^= 1;
  }

#pragma unroll
  for (int bn = 0; bn < 4; ++bn) {
    int c = n0 + wn * 64 + bn * 16 + l15;
    float bv = bias ? bias[c] : 0.f;
#pragma unroll
    for (int am = 0; am < 4; ++am) {
#pragma unroll
      for (int jj = 0; jj < 4; ++jj) {
        int r = m0 + wm * 64 + am * 16 + l4 * 4 + jj;
        C[(size_t)r * F_ + c] = f2bf((acc[am][bn][jj] + bv) * osc);
      }
    }
  }
}

// ---------------- flash attention, bf16 MFMA, swapped QK^T ---------------
// R3 structure (proven 93us): KVBLK=64 double-buffered global_load_lds.
// Q pre-scaled by (1/sqrt(128))*log2(e) in gemm epilogue -> softmax in
// log2 domain, no per-element scale mult. T13 defer-max. T5 setprio.
// v_cvt_pk_bf16_f32 for P pack.
__global__ __launch_bounds__(256, 2)
void attn_mfma(const unsigned short* __restrict__ Q,
               const unsigned short* __restrict__ K,
               const unsigned short* __restrict__ Vt,
               const float* __restrict__ vb,
               float* __restrict__ out) {
  __shared__ unsigned short Kt[2][64 * 128];
  __shared__ unsigned short Vts[2][128 * 64];
  __shared__ unsigned short Pt[4][16 * 64];
  const int tid = threadIdx.x, lane = tid & 63, wv = tid >> 6;
  const int l15 = lane & 15, l4 = lane >> 4;
  const int g = blockIdx.y;
  const int q0 = blockIdx.x * 64 + wv * 16;

  s16x8 qa[4];
#pragma unroll
  for (int kc = 0; kc < 4; ++kc)
    qa[kc] = *(const s16x8*)(Q + (size_t)(q0 + l15) * F_ + g * DG_ + kc * 32 + l4 * 8);

  f32x4 oa[8];
#pragma unroll
  for (int df = 0; df < 8; ++df) oa[df] = (f32x4){0.f, 0.f, 0.f, 0.f};
  float m_r = -1e30f, l_r = 0.f;

  // pre-swizzled global offsets for global_load_lds staging
  const int ksw0 = (((lane & 15) ^ (lane >> 4)) * 8);
  const int ksw1 = (((lane & 15) ^ 4 ^ (lane >> 4)) * 8);
  const int vsw  = (((lane & 7) ^ (lane >> 3)) * 8);
  const int xorb = (l15 & 7) << 4;
  int csw[4];
#pragma unroll
  for (int kc = 0; kc < 4; ++kc) csw[kc] = (kc * 64 + l4 * 16) ^ xorb;

  auto stage = [&](int buf, int kv0) {
#pragma unroll
    for (int i = 0; i < 4; ++i) {   // K tile: 4 rows (256B) per instr
      int r0 = wv * 16 + i * 4;
      __builtin_amdgcn_global_load_lds(
          (GV*)(K + (size_t)(kv0 + r0 + (lane >> 4)) * F_ + g * DG_ + ((i & 1) ? ksw1 : ksw0)),
          (LV*)(&Kt[buf][r0 * 128]), 16, 0, 0);
    }
#pragma unroll
    for (int i = 0; i < 4; ++i) {   // V^T tile: 8 rows (128B) per instr
      int r0 = wv * 32 + i * 8;
      __builtin_amdgcn_global_load_lds(
          (GV*)(Vt + (size_t)(g * DG_ + r0 + (lane >> 3)) * M_ + kv0 + vsw),
          (LV*)(&Vts[buf][r0 * 64]), 16, 0, 0);
    }
  };

  stage(0, 0);
  __syncthreads();
  int cur = 0;
  unsigned short* Pw = &Pt[wv][0];

  for (int t = 0; t < M_ / 64; ++t) {
    if (t + 1 < M_ / 64) stage(cur ^ 1, (t + 1) * 64);
    const unsigned short* Kb = &Kt[cur][0];
    const unsigned short* Vb = &Vts[cur][0];

    // ---- S^T = K Q^T : lane q=l15, kv = kvf*16 + l4*4 + j (log2 domain) --
    f32x4 sf[4];
    __builtin_amdgcn_s_setprio(1);
#pragma unroll
    for (int kvf = 0; kvf < 4; ++kvf) {
      f32x4 s = (f32x4){0.f, 0.f, 0.f, 0.f};
#pragma unroll
      for (int kc = 0; kc < 4; ++kc) {
        s16x8 kf = *(const s16x8*)((const char*)Kb + (kvf * 16 + l15) * 256 + csw[kc]);
        s = __builtin_amdgcn_mfma_f32_16x16x32_bf16(kf, qa[kc], s, 0, 0, 0);
      }
      sf[kvf] = s;
    }
    __builtin_amdgcn_s_setprio(0);

    // ---- online softmax with defer-max (THR=8, log2 domain) ----
    float tmax = sf[0][0];
#pragma unroll
    for (int kvf = 0; kvf < 4; ++kvf) {
      tmax = fmaxf(tmax, fmaxf(fmaxf(sf[kvf][0], sf[kvf][1]),
                               fmaxf(sf[kvf][2], sf[kvf][3])));
    }
    tmax = fmaxf(tmax, __shfl_xor(tmax, 16));
    tmax = fmaxf(tmax, __shfl_xor(tmax, 32));
    if (!__all(tmax <= m_r + 8.0f)) {
      float mnew = fmaxf(m_r, tmax);
      float corr = __builtin_amdgcn_exp2f(m_r - mnew);
      m_r = mnew;
      l_r *= corr;
      float c0 = __shfl(corr, l4 * 4 + 0);
      float c1 = __shfl(corr, l4 * 4 + 1);
      float c2 = __shfl(corr, l4 * 4 + 2);
      float c3 = __shfl(corr, l4 * 4 + 3);
#pragma unroll
      for (int df = 0; df < 8; ++df) {
        oa[df][0] *= c0; oa[df][1] *= c1; oa[df][2] *= c2; oa[df][3] *= c3;
      }
    }

    float psum = 0.f;
#pragma unroll
    for (int kvf = 0; kvf < 4; ++kvf) {
      float p0 = __builtin_amdgcn_exp2f(sf[kvf][0] - m_r);
      float p1 = __builtin_amdgcn_exp2f(sf[kvf][1] - m_r);
      float p2 = __builtin_amdgcn_exp2f(sf[kvf][2] - m_r);
      float p3 = __builtin_amdgcn_exp2f(sf[kvf][3] - m_r);
      psum += (p0 + p1) + (p2 + p3);
      u32x2 w;
      asm("v_cvt_pk_bf16_f32 %0, %1, %2" : "=v"(w.x) : "v"(p0), "v"(p1));
      asm("v_cvt_pk_bf16_f32 %0, %1, %2" : "=v"(w.y) : "v"(p2), "v"(p3));
      *(u32x2*)((char*)Pw + l15 * 128 + ((kvf * 32 + l4 * 8) ^ xorb)) = w;
    }
    psum += __shfl_xor(psum, 16);
    psum += __shfl_xor(psum, 32);
    l_r += psum;

    // ---- O += P V : A = P rows (q=l15), B = V^T rows (d) ----
    s16x8 pa0 = *(const s16x8*)((const char*)Pw + l15 * 128 + csw[0]);
    s16x8 pa1 = *(const s16x8*)((const char*)Pw + l15 * 128 + csw[1]);
    __builtin_amdgcn_s_setprio(1);
#pragma unroll
    for (int df = 0; df < 8; ++df) {
      s16x8 v0 = *(const s16x8*)((const char*)Vb + (df * 16 + l15) * 128 + csw[0]);
      s16x8 v1 = *(const s16x8*)((const char*)Vb + (df * 16 + l15) * 128 + csw[1]);
      oa[df] = __builtin_amdgcn_mfma_f32_16x16x32_bf16(pa0, v0, oa[df], 0, 0, 0);
      oa[df] = __builtin_amdgcn_mfma_f32_16x16x32_bf16(pa1, v1, oa[df], 0, 0, 0);
    }
    __builtin_amdgcn_s_setprio(0);
    __syncthreads();
    cur ^= 1;
  }

  // ---- epilogue ----
  float linv = 1.0f / l_r;
  float i0 = __shfl(linv, l4 * 4 + 0);
  float i1 = __shfl(linv, l4 * 4 + 1);
  float i2 = __shfl(linv, l4 * 4 + 2);
  float i3 = __shfl(linv, l4 * 4 + 3);
#pragma unroll
  for (int df = 0; df < 8; ++df) {
    int c = g * DG_ + df * 16 + l15;
    float bv = vb[c];
    out[(size_t)(q0 + l4 * 4 + 0) * F_ + c] = oa[df][0] * i0 + bv;
    out[(size_t)(q0 + l4 * 4 + 1) * F_ + c] = oa[df][1] * i1 + bv;
    out[(size_t)(q0 + l4 * 4 + 2) * F_ + c] = oa[df][2] * i2 + bv;
    out[(size_t)(q0 + l4 * 4 + 3) * F_ + c] = oa[df][3] * i3 + bv;
  }
}

extern "C" void kernel_launch(void* const* d_in, const int* in_sizes, int n_in,
                              void* d_out, int out_size, void* d_ws, size_t ws_size,
                              hipStream_t stream) {
  const float* roi  = (const float*)d_in[0];
  const float* ref  = (const float*)d_in[1];
  const float* Wq_w = (const float*)d_in[2];
  const float* Wq_b = (const float*)d_in[3];
  const float* Wk_w = (const float*)d_in[4];
  const float* Wk_b = (const float*)d_in[5];
  const float* Wv_w = (const float*)d_in[6];
  const float* Wv_b = (const float*)d_in[7];
  float* out = (float*)d_out;
  const size_t SEG = 4194304;  // 8 MB / 2B
  const float cscale = 0.12751664508246770f;  // (1/sqrt(128)) * log2(e)

  if (ws_size >= 64ull * 1024 * 1024) {
    unsigned short* roi_bf = (unsigned short*)d_ws;
    unsigned short* ref_bf = roi_bf + SEG;
    unsigned short* Wq_bf  = ref_bf + SEG;
    unsigned short* Wk_bf  = Wq_bf + SEG;
    unsigned short* Wv_bf  = Wk_bf + SEG;
    unsigned short* Qb     = Wv_bf + SEG;
    unsigned short* Kb     = Qb + SEG;
    unsigned short* Vtb    = Kb + SEG;

    Cvt5Args ca;
    ca.s[0] = roi;  ca.d[0] = roi_bf;
    ca.s[1] = ref;  ca.d[1] = ref_bf;
    ca.s[2] = Wq_w; ca.d[2] = Wq_bf;
    ca.s[3] = Wk_w; ca.d[3] = Wk_bf;
    ca.s[4] = Wv_w; ca.d[4] = Wv_bf;
    cvt5<<<10240, 256, 0, stream>>>(ca);

    GemmJobs jb;
    jb.A[0] = roi_bf; jb.B[0] = Wq_bf;  jb.bias[0] = Wq_b;    jb.C[0] = Qb;  jb.osc[0] = cscale;
    jb.A[1] = ref_bf; jb.B[1] = Wk_bf;  jb.bias[1] = Wk_b;    jb.C[1] = Kb;  jb.osc[1] = 1.0f;
    jb.A[2] = Wv_bf;  jb.B[2] = ref_bf; jb.bias[2] = nullptr; jb.C[2] = Vtb; jb.osc[2] = 1.0f;
    gemm3<<<768, 256, 0, stream>>>(jb, 0);

    attn_mfma<<<dim3(N_ / 64, G_), 256, 0, stream>>>(Qb, Kb, Vtb, Wv_b, out);
  } else {
    if (ws_size < 48ull * 1024 * 1024) return;
    unsigned short* roi_bf = (unsigned short*)d_ws;
    unsigned short* ref_bf = roi_bf + SEG;
    unsigned short* W_bf   = ref_bf + SEG;
    unsigned short* Qb     = W_bf + SEG;
    unsigned short* Kb     = Qb + SEG;
    unsigned short* Vtb    = Kb + SEG;
    const int n8 = (N_ * F_) / 8;

    cvt_bf16<<<2048, 256, 0, stream>>>(roi, roi_bf, n8);
    cvt_bf16<<<2048, 256, 0, stream>>>(ref, ref_bf, n8);

    GemmJobs jb;
    jb.A[0] = roi_bf; jb.B[0] = W_bf;   jb.bias[0] = Wq_b;    jb.C[0] = Qb;  jb.osc[0] = cscale;
    jb.A[1] = ref_bf; jb.B[1] = W_bf;   jb.bias[1] = Wk_b;    jb.C[1] = Kb;  jb.osc[1] = 1.0f;
    jb.A[2] = W_bf;   jb.B[2] = ref_bf; jb.bias[2] = nullptr; jb.C[2] = Vtb; jb.osc[2] = 1.0f;

    cvt_bf16<<<2048, 256, 0, stream>>>(Wq_w, W_bf, n8);
    gemm3<<<256, 256, 0, stream>>>(jb, 0);
    cvt_bf16<<<2048, 256, 0, stream>>>(Wk_w, W_bf, n8);
    gemm3<<<256, 256, 0, stream>>>(jb, 1);
    cvt_bf16<<<2048, 256, 0, stream>>>(Wv_w, W_bf, n8);
    gemm3<<<256, 256, 0, stream>>>(jb, 2);

    attn_mfma<<<dim3(N_ / 64, G_), 256, 0, stream>>>(Qb, Kb, Vtb, Wv_b, out);
  }
}

// Round 7
// 141.635 us; speedup vs baseline: 2.0904x; 1.0610x over previous
//
#include <hip/hip_runtime.h>
#include <hip/hip_bf16.h>

#define G_   16
#define DG_  128
#define F_   2048
#define N_   2048
#define M_   2048

typedef __attribute__((ext_vector_type(8))) short s16x8;   // 8 bf16 (4 VGPRs)
typedef __attribute__((ext_vector_type(4))) float f32x4;
typedef __attribute__((ext_vector_type(2))) unsigned int u32x2;

typedef const __attribute__((address_space(1))) void GV;
typedef __attribute__((address_space(3))) void LV;

__device__ inline unsigned short f2bf(float f) {           // RN-even fp32->bf16
  unsigned u = __float_as_uint(f);
  u += 0x7fffu + ((u >> 16) & 1u);
  return (unsigned short)(u >> 16);
}

// ---------------- fp32 -> bf16 convert: 5 arrays in one launch -----------
struct Cvt5Args { const float* s[5]; unsigned short* d[5]; };

__global__ __launch_bounds__(256)
void cvt5(Cvt5Args a) {
  unsigned u = blockIdx.x * 256 + threadIdx.x;
  if (u >= 5u * 524288u) return;
  int seg = u >> 19;                 // 524288 = 2^19 eights per 4M array
  unsigned off = u & 524287u;
  const float4* sp = (const float4*)(a.s[seg] + (size_t)off * 8);
  float4 x = sp[0], y = sp[1];
  uint4 o;
  o.x = (unsigned)f2bf(x.x) | ((unsigned)f2bf(x.y) << 16);
  o.y = (unsigned)f2bf(x.z) | ((unsigned)f2bf(x.w) << 16);
  o.z = (unsigned)f2bf(y.x) | ((unsigned)f2bf(y.y) << 16);
  o.w = (unsigned)f2bf(y.z) | ((unsigned)f2bf(y.w) << 16);
  *(uint4*)(a.d[seg] + (size_t)off * 8) = o;
}

// ---------------- bf16 NT GEMM, 3 jobs, 256x256 8-phase ------------------
// BM=BN=256, BK=64, 512 thr (8 waves, 2M x 4N), LDS 128KB (2 buf x (A+B)).
// Per K-tile: 4 phases {ds_read subtile | 1 half-tile gload_lds prefetch |
// s_barrier | lgkmcnt(0) | 16 MFMA (setprio) | s_barrier}; vmcnt(0) once
// per K-tile (before the last barrier). Swizzle byte^=(row&7)<<4 with
// pre-swizzled global source (linear LDS dest).
struct GemmJobs {
  const unsigned short* A[3];
  const unsigned short* B[3];
  const float* bias[3];
  unsigned short* C[3];
  float osc[3];
};

__global__ __launch_bounds__(512, 2)
void gemm8(GemmJobs jb) {
  __shared__ __align__(16) char lds[131072];
  const int j  = blockIdx.x >> 6;
  const int bs = blockIdx.x & 63;
  const unsigned short* A = jb.A[j];
  const unsigned short* B = jb.B[j];
  const float* bias = jb.bias[j];
  unsigned short* C = jb.C[j];
  const float osc = jb.osc[j];

  const int tid = threadIdx.x, lane = tid & 63, wv = tid >> 6;
  const int wm = wv >> 2, wn = wv & 3;            // 2 x 4 wave grid
  const int l15 = lane & 15, l4 = lane >> 4;
  const int m0 = (bs >> 3) * 256, n0 = (bs & 7) * 256;
  const int xo  = (l15 & 7) << 4;
  const int ksw = ((lane & 7) ^ (lane >> 3)) * 8;  // pre-swizzled src col
  const int brr0 = (wn & 1) * 64;

  f32x4 acc[8][4];
#pragma unroll
  for (int i = 0; i < 8; ++i)
#pragma unroll
    for (int nf = 0; nf < 4; ++nf) acc[i][nf] = (f32x4){0.f, 0.f, 0.f, 0.f};

  // one half-tile (128 rows x 64 cols) = 2 gload_lds calls (8KB each)
  auto stage_half = [&](int buf2, const unsigned short* Mat, int lbase,
                        int h, int row0, int k0) {
#pragma unroll
    for (int c = 0; c < 2; ++c) {
      __builtin_amdgcn_global_load_lds(
          (GV*)(Mat + (size_t)(row0 + h * 128 + c * 64 + wv * 8 + (lane >> 3)) * F_
                + k0 + ksw),
          (LV*)(lds + buf2 * 65536 + lbase + h * 16384 + c * 8192 + wv * 1024),
          16, 0, 0);
    }
  };

  // prologue: K-tile 0 -> buf 0
  stage_half(0, A, 0,     0, m0, 0);
  stage_half(0, A, 0,     1, m0, 0);
  stage_half(0, B, 32768, 0, n0, 0);
  stage_half(0, B, 32768, 1, n0, 0);
  asm volatile("s_waitcnt vmcnt(0)" ::: "memory");
  __builtin_amdgcn_sched_barrier(0);
  __builtin_amdgcn_s_barrier();

  const int NT = F_ / 64;
  for (int t = 0; t < NT; ++t) {
    const int buf = t & 1;
    const char* Ab = lds + buf * 65536 + wm * 16384;
    const char* Bb = lds + buf * 65536 + 32768 + (wn >> 1) * 16384;
    const bool pf = (t + 1 < NT);
    const int k1 = (t + 1) * 64;
    s16x8 af[4], bf[4];

    auto ldA = [&](int mf, int ks) {
      return *(const s16x8*)(Ab + (mf * 16 + l15) * 128 + ((ks * 64 + l4 * 16) ^ xo));
    };
    auto ldB = [&](int nf, int ks) {
      return *(const s16x8*)(Bb + (brr0 + nf * 16 + l15) * 128 + ((ks * 64 + l4 * 16) ^ xo));
    };

    // ---- phase 0: ks=0, mf 0-3 (reads bf ks0 + af; stage A half0) ----
#pragma unroll
    for (int nf = 0; nf < 4; ++nf) bf[nf] = ldB(nf, 0);
#pragma unroll
    for (int i = 0; i < 4; ++i) af[i] = ldA(i, 0);
    if (pf) stage_half(buf ^ 1, A, 0, 0, m0, k1);
    __builtin_amdgcn_sched_barrier(0);
    __builtin_amdgcn_s_barrier();
    asm volatile("s_waitcnt lgkmcnt(0)" ::: "memory");
    __builtin_amdgcn_sched_barrier(0);
    __builtin_amdgcn_s_setprio(1);
#pragma unroll
    for (int i = 0; i < 4; ++i)
#pragma unroll
      for (int nf = 0; nf < 4; ++nf)
        acc[i][nf] = __builtin_amdgcn_mfma_f32_16x16x32_bf16(af[i], bf[nf], acc[i][nf], 0, 0, 0);
    __builtin_amdgcn_s_setprio(0);
    __builtin_amdgcn_sched_barrier(0);
    __builtin_amdgcn_s_barrier();

    // ---- phase 1: ks=0, mf 4-7 (stage A half1) ----
#pragma unroll
    for (int i = 0; i < 4; ++i) af[i] = ldA(4 + i, 0);
    if (pf) stage_half(buf ^ 1, A, 0, 1, m0, k1);
    __builtin_amdgcn_sched_barrier(0);
    __builtin_amdgcn_s_barrier();
    asm volatile("s_waitcnt lgkmcnt(0)" ::: "memory");
    __builtin_amdgcn_sched_barrier(0);
    __builtin_amdgcn_s_setprio(1);
#pragma unroll
    for (int i = 0; i < 4; ++i)
#pragma unroll
      for (int nf = 0; nf < 4; ++nf)
        acc[4 + i][nf] = __builtin_amdgcn_mfma_f32_16x16x32_bf16(af[i], bf[nf], acc[4 + i][nf], 0, 0, 0);
    __builtin_amdgcn_s_setprio(0);
    __builtin_amdgcn_sched_barrier(0);
    __builtin_amdgcn_s_barrier();

    // ---- phase 2: ks=1, mf 0-3 (reads bf ks1 + af; stage B half0) ----
#pragma unroll
    for (int nf = 0; nf < 4; ++nf) bf[nf] = ldB(nf, 1);
#pragma unroll
    for (int i = 0; i < 4; ++i) af[i] = ldA(i, 1);
    if (pf) stage_half(buf ^ 1, B, 32768, 0, n0, k1);
    __builtin_amdgcn_sched_barrier(0);
    __builtin_amdgcn_s_barrier();
    asm volatile("s_waitcnt lgkmcnt(0)" ::: "memory");
    __builtin_amdgcn_sched_barrier(0);
    __builtin_amdgcn_s_setprio(1);
#pragma unroll
    for (int i = 0; i < 4; ++i)
#pragma unroll
      for (int nf = 0; nf < 4; ++nf)
        acc[i][nf] = __builtin_amdgcn_mfma_f32_16x16x32_bf16(af[i], bf[nf], acc[i][nf], 0, 0, 0);
    __builtin_amdgcn_s_setprio(0);
    __builtin_amdgcn_sched_barrier(0);
    __builtin_amdgcn_s_barrier();

    // ---- phase 3: ks=1, mf 4-7 (stage B half1; vmcnt(0) before flip) ----
#pragma unroll
    for (int i = 0; i < 4; ++i) af[i] = ldA(4 + i, 1);
    if (pf) stage_half(buf ^ 1, B, 32768, 1, n0, k1);
    __builtin_amdgcn_sched_barrier(0);
    __builtin_amdgcn_s_barrier();
    asm volatile("s_waitcnt lgkmcnt(0)" ::: "memory");
    __builtin_amdgcn_sched_barrier(0);
    __builtin_amdgcn_s_setprio(1);
#pragma unroll
    for (int i = 0; i < 4; ++i)
#pragma unroll
      for (int nf = 0; nf < 4; ++nf)
        acc[4 + i][nf] = __builtin_amdgcn_mfma_f32_16x16x32_bf16(af[i], bf[nf], acc[4 + i][nf], 0, 0, 0);
    __builtin_amdgcn_s_setprio(0);
    asm volatile("s_waitcnt vmcnt(0)" ::: "memory");   // own prefetches landed
    __builtin_amdgcn_sched_barrier(0);
    __builtin_amdgcn_s_barrier();                      // all waves' loads landed
  }

  // ---- epilogue ----
#pragma unroll
  for (int nf = 0; nf < 4; ++nf) {
    int c = n0 + wn * 64 + nf * 16 + l15;
    float bv = bias ? bias[c] : 0.f;
#pragma unroll
    for (int mf = 0; mf < 8; ++mf) {
#pragma unroll
      for (int jj = 0; jj < 4; ++jj) {
        int r = m0 + wm * 128 + mf * 16 + l4 * 4 + jj;
        C[(size_t)r * F_ + c] = f2bf((acc[mf][nf][jj] + bv) * osc);
      }
    }
  }
}

// ---------------- flash attention, bf16 MFMA, swapped QK^T ---------------
// R3/R6 proven: KVBLK=64 double-buffered global_load_lds; Q pre-scaled by
// (1/sqrt(128))*log2(e); T13 defer-max; T5 setprio; cvt_pk P pack.
__global__ __launch_bounds__(256, 2)
void attn_mfma(const unsigned short* __restrict__ Q,
               const unsigned short* __restrict__ K,
               const unsigned short* __restrict__ Vt,
               const float* __restrict__ vb,
               float* __restrict__ out) {
  __shared__ unsigned short Kt[2][64 * 128];
  __shared__ unsigned short Vts[2][128 * 64];
  __shared__ unsigned short Pt[4][16 * 64];
  const int tid = threadIdx.x, lane = tid & 63, wv = tid >> 6;
  const int l15 = lane & 15, l4 = lane >> 4;
  const int g = blockIdx.y;
  const int q0 = blockIdx.x * 64 + wv * 16;

  s16x8 qa[4];
#pragma unroll
  for (int kc = 0; kc < 4; ++kc)
    qa[kc] = *(const s16x8*)(Q + (size_t)(q0 + l15) * F_ + g * DG_ + kc * 32 + l4 * 8);

  f32x4 oa[8];
#pragma unroll
  for (int df = 0; df < 8; ++df) oa[df] = (f32x4){0.f, 0.f, 0.f, 0.f};
  float m_r = -1e30f, l_r = 0.f;

  const int ksw0 = (((lane & 15) ^ (lane >> 4)) * 8);
  const int ksw1 = (((lane & 15) ^ 4 ^ (lane >> 4)) * 8);
  const int vsw  = (((lane & 7) ^ (lane >> 3)) * 8);
  const int xorb = (l15 & 7) << 4;
  int csw[4];
#pragma unroll
  for (int kc = 0; kc < 4; ++kc) csw[kc] = (kc * 64 + l4 * 16) ^ xorb;

  auto stage = [&](int buf, int kv0) {
#pragma unroll
    for (int i = 0; i < 4; ++i) {   // K tile: 4 rows (256B) per instr
      int r0 = wv * 16 + i * 4;
      __builtin_amdgcn_global_load_lds(
          (GV*)(K + (size_t)(kv0 + r0 + (lane >> 4)) * F_ + g * DG_ + ((i & 1) ? ksw1 : ksw0)),
          (LV*)(&Kt[buf][r0 * 128]), 16, 0, 0);
    }
#pragma unroll
    for (int i = 0; i < 4; ++i) {   // V^T tile: 8 rows (128B) per instr
      int r0 = wv * 32 + i * 8;
      __builtin_amdgcn_global_load_lds(
          (GV*)(Vt + (size_t)(g * DG_ + r0 + (lane >> 3)) * M_ + kv0 + vsw),
          (LV*)(&Vts[buf][r0 * 64]), 16, 0, 0);
    }
  };

  stage(0, 0);
  __syncthreads();
  int cur = 0;
  unsigned short* Pw = &Pt[wv][0];

  for (int t = 0; t < M_ / 64; ++t) {
    if (t + 1 < M_ / 64) stage(cur ^ 1, (t + 1) * 64);
    const unsigned short* Kb = &Kt[cur][0];
    const unsigned short* Vb = &Vts[cur][0];

    // ---- S^T = K Q^T : lane q=l15, kv = kvf*16 + l4*4 + j (log2 domain) --
    f32x4 sf[4];
    __builtin_amdgcn_s_setprio(1);
#pragma unroll
    for (int kvf = 0; kvf < 4; ++kvf) {
      f32x4 s = (f32x4){0.f, 0.f, 0.f, 0.f};
#pragma unroll
      for (int kc = 0; kc < 4; ++kc) {
        s16x8 kf = *(const s16x8*)((const char*)Kb + (kvf * 16 + l15) * 256 + csw[kc]);
        s = __builtin_amdgcn_mfma_f32_16x16x32_bf16(kf, qa[kc], s, 0, 0, 0);
      }
      sf[kvf] = s;
    }
    __builtin_amdgcn_s_setprio(0);

    // ---- online softmax with defer-max (THR=8, log2 domain) ----
    float tmax = sf[0][0];
#pragma unroll
    for (int kvf = 0; kvf < 4; ++kvf) {
      tmax = fmaxf(tmax, fmaxf(fmaxf(sf[kvf][0], sf[kvf][1]),
                               fmaxf(sf[kvf][2], sf[kvf][3])));
    }
    tmax = fmaxf(tmax, __shfl_xor(tmax, 16));
    tmax = fmaxf(tmax, __shfl_xor(tmax, 32));
    if (!__all(tmax <= m_r + 8.0f)) {
      float mnew = fmaxf(m_r, tmax);
      float corr = __builtin_amdgcn_exp2f(m_r - mnew);
      m_r = mnew;
      l_r *= corr;
      float c0 = __shfl(corr, l4 * 4 + 0);
      float c1 = __shfl(corr, l4 * 4 + 1);
      float c2 = __shfl(corr, l4 * 4 + 2);
      float c3 = __shfl(corr, l4 * 4 + 3);
#pragma unroll
      for (int df = 0; df < 8; ++df) {
        oa[df][0] *= c0; oa[df][1] *= c1; oa[df][2] *= c2; oa[df][3] *= c3;
      }
    }

    float psum = 0.f;
#pragma unroll
    for (int kvf = 0; kvf < 4; ++kvf) {
      float p0 = __builtin_amdgcn_exp2f(sf[kvf][0] - m_r);
      float p1 = __builtin_amdgcn_exp2f(sf[kvf][1] - m_r);
      float p2 = __builtin_amdgcn_exp2f(sf[kvf][2] - m_r);
      float p3 = __builtin_amdgcn_exp2f(sf[kvf][3] - m_r);
      psum += (p0 + p1) + (p2 + p3);
      u32x2 w;
      asm("v_cvt_pk_bf16_f32 %0, %1, %2" : "=v"(w.x) : "v"(p0), "v"(p1));
      asm("v_cvt_pk_bf16_f32 %0, %1, %2" : "=v"(w.y) : "v"(p2), "v"(p3));
      *(u32x2*)((char*)Pw + l15 * 128 + ((kvf * 32 + l4 * 8) ^ xorb)) = w;
    }
    psum += __shfl_xor(psum, 16);
    psum += __shfl_xor(psum, 32);
    l_r += psum;

    // ---- O += P V : A = P rows (q=l15), B = V^T rows (d) ----
    s16x8 pa0 = *(const s16x8*)((const char*)Pw + l15 * 128 + csw[0]);
    s16x8 pa1 = *(const s16x8*)((const char*)Pw + l15 * 128 + csw[1]);
    __builtin_amdgcn_s_setprio(1);
#pragma unroll
    for (int df = 0; df < 8; ++df) {
      s16x8 v0 = *(const s16x8*)((const char*)Vb + (df * 16 + l15) * 128 + csw[0]);
      s16x8 v1 = *(const s16x8*)((const char*)Vb + (df * 16 + l15) * 128 + csw[1]);
      oa[df] = __builtin_amdgcn_mfma_f32_16x16x32_bf16(pa0, v0, oa[df], 0, 0, 0);
      oa[df] = __builtin_amdgcn_mfma_f32_16x16x32_bf16(pa1, v1, oa[df], 0, 0, 0);
    }
    __builtin_amdgcn_s_setprio(0);
    __syncthreads();
    cur ^= 1;
  }

  // ---- epilogue ----
  float linv = 1.0f / l_r;
  float i0 = __shfl(linv, l4 * 4 + 0);
  float i1 = __shfl(linv, l4 * 4 + 1);
  float i2 = __shfl(linv, l4 * 4 + 2);
  float i3 = __shfl(linv, l4 * 4 + 3);
#pragma unroll
  for (int df = 0; df < 8; ++df) {
    int c = g * DG_ + df * 16 + l15;
    float bv = vb[c];
    out[(size_t)(q0 + l4 * 4 + 0) * F_ + c] = oa[df][0] * i0 + bv;
    out[(size_t)(q0 + l4 * 4 + 1) * F_ + c] = oa[df][1] * i1 + bv;
    out[(size_t)(q0 + l4 * 4 + 2) * F_ + c] = oa[df][2] * i2 + bv;
    out[(size_t)(q0 + l4 * 4 + 3) * F_ + c] = oa[df][3] * i3 + bv;
  }
}

extern "C" void kernel_launch(void* const* d_in, const int* in_sizes, int n_in,
                              void* d_out, int out_size, void* d_ws, size_t ws_size,
                              hipStream_t stream) {
  const float* roi  = (const float*)d_in[0];
  const float* ref  = (const float*)d_in[1];
  const float* Wq_w = (const float*)d_in[2];
  const float* Wq_b = (const float*)d_in[3];
  const float* Wk_w = (const float*)d_in[4];
  const float* Wk_b = (const float*)d_in[5];
  const float* Wv_w = (const float*)d_in[6];
  const float* Wv_b = (const float*)d_in[7];
  float* out = (float*)d_out;
  const size_t SEG = 4194304;  // 8 MB / 2B
  const float cscale = 0.12751664508246770f;  // (1/sqrt(128)) * log2(e)

  if (ws_size < 64ull * 1024 * 1024) return;
  unsigned short* roi_bf = (unsigned short*)d_ws;
  unsigned short* ref_bf = roi_bf + SEG;
  unsigned short* Wq_bf  = ref_bf + SEG;
  unsigned short* Wk_bf  = Wq_bf + SEG;
  unsigned short* Wv_bf  = Wk_bf + SEG;
  unsigned short* Qb     = Wv_bf + SEG;
  unsigned short* Kb     = Qb + SEG;
  unsigned short* Vtb    = Kb + SEG;

  Cvt5Args ca;
  ca.s[0] = roi;  ca.d[0] = roi_bf;
  ca.s[1] = ref;  ca.d[1] = ref_bf;
  ca.s[2] = Wq_w; ca.d[2] = Wq_bf;
  ca.s[3] = Wk_w; ca.d[3] = Wk_bf;
  ca.s[4] = Wv_w; ca.d[4] = Wv_bf;
  cvt5<<<10240, 256, 0, stream>>>(ca);

  GemmJobs jb;
  jb.A[0] = roi_bf; jb.B[0] = Wq_bf;  jb.bias[0] = Wq_b;    jb.C[0] = Qb;  jb.osc[0] = cscale;
  jb.A[1] = ref_bf; jb.B[1] = Wk_bf;  jb.bias[1] = Wk_b;    jb.C[1] = Kb;  jb.osc[1] = 1.0f;
  jb.A[2] = Wv_bf;  jb.B[2] = ref_bf; jb.bias[2] = nullptr; jb.C[2] = Vtb; jb.osc[2] = 1.0f;
  gemm8<<<192, 512, 0, stream>>>(jb);

  attn_mfma<<<dim3(N_ / 64, G_), 256, 0, stream>>>(Qb, Kb, Vtb, Wv_b, out);
}